// Round 6
// baseline (79.002 us; speedup 1.0000x reference)
//
#include <hip/hip_runtime.h>
#include <hip/hip_bf16.h>

// Problem constants
constexpr int BB = 8;
constexpr int LLEN = 2048;
constexpr int HH = 256;
constexpr int EE = 512;          // H * EXP
constexpr int MM = BB * LLEN;    // 16384 rows

typedef short bf16x8 __attribute__((ext_vector_type(8)));
typedef float f32x4  __attribute__((ext_vector_type(4)));

static __device__ inline unsigned short f2bf(float f) {
    unsigned u = __builtin_bit_cast(unsigned, f);
    unsigned r = (u + 0x7FFFu + ((u >> 16) & 1u)) >> 16;
    return (unsigned short)r;
}
static __device__ inline float bf2f(unsigned short h) {
    return __builtin_bit_cast(float, (unsigned)h << 16);
}

#define GL2LDS(gp, lp) __builtin_amdgcn_global_load_lds( \
    (const __attribute__((address_space(1))) void*)(gp), \
    (__attribute__((address_space(3))) void*)(lp), 16, 0, 0)

// ---------------------------------------------------------------------------
// Wt[n][k] = (bf16) W[k][n]   (output-contiguous)
// ---------------------------------------------------------------------------
__global__ __launch_bounds__(256) void transpose_cast_kernel(
    const float* __restrict__ W, unsigned short* __restrict__ Wt, int K, int N)
{
    int i = blockIdx.x * 256 + threadIdx.x;
    if (i < K * N) {
        int n = i / K, k = i - n * K;
        Wt[i] = f2bf(W[(size_t)k * N + n]);
    }
}

// ---------------------------------------------------------------------------
// KA: fused cast + GEMM1.  xz = u(f32->bf16) @ W_in^T + b_in.
// 128x128 tile, K=256 staged ONCE (A 64KB reg-staged cvt, B 64KB via
// global_load_lds), one barrier, 8 unbarriered K-steps of 16 MFMA.
// Split epilogue: cols<512 -> x bf16; cols>=512 -> silu -> zs bf16.
// LDS swizzle: 16B slot s of row r at phys s^(r&7) (A: cvt path writes
// swizzled; B: pre-swizzled global source, linear LDS dest).
// Grid 1024 = 8 XCDs x 128; lin = (b&7)*128+(b>>3); row0=(lin>>3), col0=(lin&7).
// ---------------------------------------------------------------------------
__global__ __launch_bounds__(256, 1) void ka_gemm1(
    const float* __restrict__ u, const unsigned short* __restrict__ Bt,
    const float* __restrict__ bias,
    unsigned short* __restrict__ xb, unsigned short* __restrict__ zsb)
{
    __shared__ unsigned short Al[128 * 256];   // 64 KB  [r][32 slots]
    __shared__ unsigned short Bl[128 * 256];   // 64 KB

    const int tid = threadIdx.x;
    const int lane = tid & 63;
    const int wave = tid >> 6;
    const int wrow = wave >> 1, wcol = wave & 1;
    const int l15 = lane & 15;
    const int lk  = lane >> 4;

    const int cpx = 128;
    const int b = blockIdx.x;
    const int lin = (b & 7) * cpx + (b >> 3);
    const int row0 = (lin >> 3) * 128;
    const int col0 = (lin & 7) * 128;

    // --- stage B (async LDS-DMA, pre-swizzled source) ---
    #pragma unroll
    for (int i = 0; i < 16; ++i) {
        int id = i * 256 + tid;
        int r = id >> 5, s = id & 31;
        GL2LDS(Bt + (size_t)(col0 + r) * 256 + ((s ^ (r & 7)) << 3), &Bl[id * 8]);
    }
    // --- stage A (f32 load -> bf16 cvt -> swizzled ds_write) ---
    #pragma unroll
    for (int i = 0; i < 16; ++i) {
        int id = i * 256 + tid;
        int r = id >> 5, s = id & 31;
        const float* up = u + (size_t)(row0 + r) * 256 + ((s ^ (r & 7)) << 3);
        float4 a0 = *reinterpret_cast<const float4*>(up);
        float4 a1 = *reinterpret_cast<const float4*>(up + 4);
        bf16x8 pk;
        pk[0] = (short)f2bf(a0.x); pk[1] = (short)f2bf(a0.y);
        pk[2] = (short)f2bf(a0.z); pk[3] = (short)f2bf(a0.w);
        pk[4] = (short)f2bf(a1.x); pk[5] = (short)f2bf(a1.y);
        pk[6] = (short)f2bf(a1.z); pk[7] = (short)f2bf(a1.w);
        *reinterpret_cast<bf16x8*>(&Al[id * 8]) = pk;
    }
    __syncthreads();   // drains vmcnt (B DMA) + lgkmcnt (A writes)

    // --- compute: 8 K-steps, no barriers ---
    f32x4 acc[4][4] = {};
    #pragma unroll
    for (int ks = 0; ks < 8; ++ks) {
        bf16x8 af[4], bfr[4];
        #pragma unroll
        for (int m = 0; m < 4; ++m) {
            const int ra = wrow * 64 + m * 16 + l15;
            const int ph = (ks * 4 + lk) ^ (ra & 7);
            af[m] = *reinterpret_cast<const bf16x8*>(&Al[ra * 256 + ph * 8]);
        }
        #pragma unroll
        for (int n = 0; n < 4; ++n) {
            const int rb = wcol * 64 + n * 16 + l15;
            const int ph = (ks * 4 + lk) ^ (rb & 7);
            bfr[n] = *reinterpret_cast<const bf16x8*>(&Bl[rb * 256 + ph * 8]);
        }
        #pragma unroll
        for (int m = 0; m < 4; ++m)
            #pragma unroll
            for (int n = 0; n < 4; ++n)
                acc[m][n] = __builtin_amdgcn_mfma_f32_16x16x32_bf16(
                    af[m], bfr[n], acc[m][n], 0, 0, 0);
    }

    // --- epilogue: col = lane&15 + .., row = (lane>>4)*4 + i ---
    #pragma unroll
    for (int m = 0; m < 4; ++m) {
        #pragma unroll
        for (int n = 0; n < 4; ++n) {
            int col = col0 + wcol * 64 + n * 16 + l15;
            float bv = bias[col];
            #pragma unroll
            for (int i = 0; i < 4; ++i) {
                int row = row0 + wrow * 64 + m * 16 + lk * 4 + i;
                float v = acc[m][n][i] + bv;
                if (col < EE) {
                    xb[(size_t)row * EE + col] = f2bf(v);
                } else {
                    float w = v / (1.f + __expf(-v));
                    zsb[(size_t)row * EE + (col - EE)] = f2bf(w);
                }
            }
        }
    }
}

// ---------------------------------------------------------------------------
// KB: fused mid + GEMM3.  Block = 64 rows.
// Phase 1: conv(k=3)+SiLU+Dp+LN+*silu(z) -> g in LDS (bf16, swizzled).
//          (SSM scan is constant over E -> cancelled by LN; W_x/b_x/A_log dead.)
// Phase 2: out = g @ W_out^T + b_out, K=512 single-shot per 64-col B-chunk.
// LDS: G 64KB + B-chunk 64KB. Grid 256 (1/CU), XCD-chunked to match KA rows.
// ---------------------------------------------------------------------------
__global__ __launch_bounds__(256, 1) void kb_mid_gemm3(
    const unsigned short* __restrict__ xb, const unsigned short* __restrict__ zsb,
    const unsigned short* __restrict__ Bt,   // wtout [256][512]
    const float* __restrict__ bias, float* __restrict__ out,
    const float* __restrict__ conv_w, const float* __restrict__ conv_b,
    const float* __restrict__ Dp, const float* __restrict__ ln_g,
    const float* __restrict__ ln_b)
{
    __shared__ unsigned short G[64 * 512];    // 64 KB  [r][64 slots]
    __shared__ unsigned short Bl[64 * 512];   // 64 KB

    const int tid = threadIdx.x;
    const int lane = tid & 63;
    const int wave = tid >> 6;
    const int l15 = lane & 15;
    const int lk  = lane >> 4;

    const int b = blockIdx.x;
    const int lin = (b & 7) * 32 + (b >> 3);  // XCD chunk (grid 256)
    const int r0 = lin * 64;

    // --- issue B chunk 0 staging (overlaps g-phase) ---
    #pragma unroll
    for (int i = 0; i < 16; ++i) {
        int id = i * 256 + tid;
        int r = id >> 6, s = id & 63;
        GL2LDS(Bt + (size_t)r * 512 + ((s ^ (r & 7)) << 3), &Bl[id * 8]);
    }

    // --- per-lane param preload (e fixed per lane: e0 = lane*8) ---
    const int e0 = lane * 8;
    float cw0[8], cw1[8], cw2[8], cb8[8], dp8[8], lg8[8], lb8[8];
    #pragma unroll
    for (int j = 0; j < 8; ++j) {
        int e = e0 + j;
        cw0[j] = conv_w[e * 3 + 0];
        cw1[j] = conv_w[e * 3 + 1];
        cw2[j] = conv_w[e * 3 + 2];
        cb8[j] = conv_b[e];
        dp8[j] = Dp[e];
        lg8[j] = ln_g[e];
        lb8[j] = ln_b[e];
    }

    // --- phase 1: g rows (wave w owns rows w*16 .. w*16+15) ---
    for (int it = 0; it < 16; ++it) {
        const int i = wave * 16 + it;
        const int gr = r0 + i;
        const int l = gr & (LLEN - 1);
        const size_t base = (size_t)gr * EE + e0;

        bf16x8 xc = *reinterpret_cast<const bf16x8*>(xb + base);
        bf16x8 xm = {}, xp = {};
        if (l > 0)        xm = *reinterpret_cast<const bf16x8*>(xb + base - EE);
        if (l < LLEN - 1) xp = *reinterpret_cast<const bf16x8*>(xb + base + EE);
        bf16x8 zv = *reinterpret_cast<const bf16x8*>(zsb + base);

        float o[8];
        float s1 = 0.f, s2 = 0.f;
        #pragma unroll
        for (int j = 0; j < 8; ++j) {
            float v = cb8[j]
                    + bf2f((unsigned short)xm[j]) * cw0[j]
                    + bf2f((unsigned short)xc[j]) * cw1[j]
                    + bf2f((unsigned short)xp[j]) * cw2[j];
            float sx = v / (1.f + __expf(-v));
            float oe = dp8[j] * sx;
            o[j] = oe;
            s1 += oe;
            s2 += oe * oe;
        }
        #pragma unroll
        for (int off = 1; off < 64; off <<= 1) {
            s1 += __shfl_xor(s1, off);
            s2 += __shfl_xor(s2, off);
        }
        const float mu  = s1 * (1.f / EE);
        const float var = s2 * (1.f / EE) - mu * mu;
        const float inv = rsqrtf(var + 1e-5f);

        bf16x8 gv;
        #pragma unroll
        for (int j = 0; j < 8; ++j) {
            float gy = ((o[j] - mu) * inv * lg8[j] + lb8[j]) * bf2f((unsigned short)zv[j]);
            gv[j] = (short)f2bf(gy);
        }
        *reinterpret_cast<bf16x8*>(&G[i * 512 + ((lane ^ (i & 7)) << 3)]) = gv;
    }
    __syncthreads();   // G complete + B chunk0 landed

    // --- phase 2: 4 N-chunks of 64, single-shot K=512 each ---
    const int wrow = wave >> 1, wcol = wave & 1;   // 2x2 waves over 64x64
    for (int c = 0; c < 4; ++c) {
        f32x4 acc[2][2] = {};
        #pragma unroll
        for (int ks = 0; ks < 16; ++ks) {
            bf16x8 af[2], bfr[2];
            #pragma unroll
            for (int m = 0; m < 2; ++m) {
                const int ra = wrow * 32 + m * 16 + l15;
                const int ph = (ks * 4 + lk) ^ (ra & 7);
                af[m] = *reinterpret_cast<const bf16x8*>(&G[ra * 512 + ph * 8]);
            }
            #pragma unroll
            for (int n = 0; n < 2; ++n) {
                const int rb = wcol * 32 + n * 16 + l15;
                const int ph = (ks * 4 + lk) ^ (rb & 7);
                bfr[n] = *reinterpret_cast<const bf16x8*>(&Bl[rb * 512 + ph * 8]);
            }
            #pragma unroll
            for (int m = 0; m < 2; ++m)
                #pragma unroll
                for (int n = 0; n < 2; ++n)
                    acc[m][n] = __builtin_amdgcn_mfma_f32_16x16x32_bf16(
                        af[m], bfr[n], acc[m][n], 0, 0, 0);
        }
        // store chunk c
        #pragma unroll
        for (int m = 0; m < 2; ++m) {
            #pragma unroll
            for (int n = 0; n < 2; ++n) {
                int col = c * 64 + wcol * 32 + n * 16 + l15;
                float bv = bias[col];
                #pragma unroll
                for (int i = 0; i < 4; ++i) {
                    int row = r0 + wrow * 32 + m * 16 + lk * 4 + i;
                    out[(size_t)row * HH + col] = acc[m][n][i] + bv;
                }
            }
        }
        // restage Bl for next chunk
        if (c < 3) {
            __syncthreads();   // all waves done reading chunk c
            #pragma unroll
            for (int i = 0; i < 16; ++i) {
                int id = i * 256 + tid;
                int r = id >> 6, s = id & 63;
                GL2LDS(Bt + (size_t)((c + 1) * 64 + r) * 512 + ((s ^ (r & 7)) << 3),
                       &Bl[id * 8]);
            }
            __syncthreads();   // chunk c+1 landed (vmcnt drained)
        }
    }
}

// ---------------------------------------------------------------------------
extern "C" void kernel_launch(void* const* d_in, const int* in_sizes, int n_in,
                              void* d_out, int out_size, void* d_ws, size_t ws_size,
                              hipStream_t stream)
{
    const float* u      = (const float*)d_in[0];
    const float* W_in   = (const float*)d_in[1];
    const float* b_in   = (const float*)d_in[2];
    const float* conv_w = (const float*)d_in[3];
    const float* conv_b = (const float*)d_in[4];
    // d_in[5]=W_x, d_in[6]=b_x, d_in[7]=A_log: dead (scan cancels under LN)
    const float* Dp     = (const float*)d_in[8];
    const float* W_out  = (const float*)d_in[9];
    const float* b_out  = (const float*)d_in[10];
    const float* ln_g   = (const float*)d_in[11];
    const float* ln_b   = (const float*)d_in[12];
    float* out = (float*)d_out;

    char* ws = (char*)d_ws;
    unsigned short* wtin  = (unsigned short*)ws; ws += (size_t)1024 * HH * 2;  // 0.5MB
    unsigned short* wtout = (unsigned short*)ws; ws += (size_t)HH * EE * 2;    // 0.25MB
    unsigned short* xbuf  = (unsigned short*)ws; ws += (size_t)MM * EE * 2;    // 16.8MB
    unsigned short* zsbuf = (unsigned short*)ws;                               // 16.8MB

    dim3 blk(256);

    transpose_cast_kernel<<<dim3((1024 * HH + 255) / 256), blk, 0, stream>>>(W_in, wtin, HH, 1024);
    transpose_cast_kernel<<<dim3((HH * EE + 255) / 256), blk, 0, stream>>>(W_out, wtout, EE, HH);

    // KA: u -> x, silu(z)   (grid 1024 = 128 row-tiles x 8 col-tiles)
    ka_gemm1<<<dim3(1024), blk, 0, stream>>>(u, wtin, b_in, xbuf, zsbuf);

    // KB: x, zs -> out      (grid 256 = 1 block/CU)
    kb_mid_gemm3<<<dim3(256), blk, 0, stream>>>(
        xbuf, zsbuf, wtout, b_out, out, conv_w, conv_b, Dp, ln_g, ln_b);
}